// Round 1
// baseline (43.708 us; speedup 1.0000x reference)
//
#include <hip/hip_runtime.h>

// out[b, l, 0:256]   = x[b, l, :]
// out[b, l, 256:512] = x[b, idxs[b,0], :]
// out[b, l, 512:768] = x[b, idxs[b,1], :]
//
// One block per output row (B*L rows), 192 threads = 3 waves.
// Each thread moves one float4 (16 B). seg = tid>>6 picks the source row,
// j = tid&63 is the float4 column within the 256-float (64-float4) segment.

__global__ __launch_bounds__(192) void info_enlarge_kernel(
    const float4* __restrict__ x4,     // [B*L*64] float4
    const int*    __restrict__ idxs,   // [B*2]
    float4*       __restrict__ out4,   // [B*L*192] float4
    int L)                             // rows per batch (1024)
{
    const int row = blockIdx.x;         // b*L + l
    const int b   = row / L;
    const int l   = row - b * L;
    const int tid = threadIdx.x;
    const int seg = tid >> 6;           // 0: self, 1: gather0, 2: gather1
    const int j   = tid & 63;           // float4 column within segment

    int src_l = l;
    if (seg > 0) src_l = idxs[b * 2 + (seg - 1)];

    const float4 v = x4[(size_t)(b * (size_t)L + src_l) * 64 + j];
    out4[(size_t)row * 192 + tid] = v;
}

extern "C" void kernel_launch(void* const* d_in, const int* in_sizes, int n_in,
                              void* d_out, int out_size, void* d_ws, size_t ws_size,
                              hipStream_t stream) {
    const float4* x4   = (const float4*)d_in[0];
    const int*    idxs = (const int*)d_in[1];
    float4*       out4 = (float4*)d_out;

    // Shapes per reference: x [B, L, D] with L=1024, D=256; idxs [B, K] with K=2.
    const int L = 1024;
    const int D = 256;
    const int B = in_sizes[0] / (L * D);

    const int rows = B * L;
    info_enlarge_kernel<<<rows, 192, 0, stream>>>(x4, idxs, out4, L);
}